// Round 7
// baseline (581.901 us; speedup 1.0000x reference)
//
#include <hip/hip_runtime.h>
#include <stdint.h>

#define N_ROWS 16384
#define DIM    512

typedef __bf16 v8bf __attribute__((ext_vector_type(8)));
typedef float  v4f  __attribute__((ext_vector_type(4)));
typedef unsigned long long u64;

union I4B8 { int4 i; v8bf b; };
__device__ __forceinline__ v8bf as_v8bf(int4 v) { I4B8 u; u.i = v; return u.b; }

// Round-to-nearest-even fp32 -> bf16
__device__ __forceinline__ ushort bf16_rne(float f) {
    unsigned u = __float_as_uint(f);
    unsigned r = u + 0x7FFFu + ((u >> 16) & 1u);
    return (ushort)(r >> 16);
}

// Monotonic float -> sortable u32 key
__device__ __forceinline__ unsigned fkey(float f) {
    unsigned u = __float_as_uint(f);
    return (u & 0x80000000u) ? ~u : (u | 0x80000000u);
}

// ---------------- kernel 1: fp32 -> bf16 convert (+ table zero-init) ----------------
__global__ __launch_bounds__(256)
void convert_bf16_kernel(const float* __restrict__ x, ushort* __restrict__ xb,
                         u64* __restrict__ table) {
    int tid    = blockIdx.x * blockDim.x + threadIdx.x;
    int stride = gridDim.x * blockDim.x;
    if (tid < N_ROWS) table[tid] = 0;
    const float4* x4  = (const float4*)x;
    ushort4*      xb4 = (ushort4*)xb;
    const int n4 = (N_ROWS * DIM) / 4;
    for (int i = tid; i < n4; i += stride) {
        float4 v = x4[i];
        ushort4 o;
        o.x = bf16_rne(v.x);
        o.y = bf16_rne(v.y);
        o.z = bf16_rne(v.z);
        o.w = bf16_rne(v.w);
        xb4[i] = o;
    }
}

// ---------------- kernel 2: symmetric tiled GEMM + fused argmax ----------------
// Triangle-fold schedule (r3): b = u*64 + p; u<=p -> (127-p,127-u), else (p,u-1).
// r7: NO LDS, NO barriers. Each wave owns a 64x64 C quadrant; A/B fragments are
// loaded straight from global (L2-hot via triangle-fold; the block's 2x2 wave
// arrangement keeps the active A/B window ~32 KB ~= L1, absorbing intra-block
// duplication). 2-deep register pipeline: load k+32 while MFMAing k; per-wave
// fine-grained vmcnt (compiler-emitted, no barrier-forced vmcnt(0) drain) is
// the restructuring the 2-barrier K-loop couldn't express (r3-r6 plateau:
// ~6800cyc/round vs ~1000cyc issue work = serial staging latency per round).
// Frag layout (m89/m91-verified): row = base+lane15, k = quad*8 + [0,8).
__global__ __launch_bounds__(256, 3)
void argmax_dots_kernel(const ushort* __restrict__ xb, u64* __restrict__ table) {
    const int u = blockIdx.x >> 6;
    const int p = blockIdx.x & 63;
    const int rT = (u <= p) ? (127 - p) : p;
    const int cT = (u <= p) ? (127 - u) : (u - 1);

    const int lane   = threadIdx.x & 63;
    const int wave   = threadIdx.x >> 6;
    const int lane15 = lane & 15;
    const int quad   = lane >> 4;
    const int rh = wave >> 1;               // row half within the 128x128 tile
    const int ch = wave & 1;                // col half

    const int rowBase = rT * 128 + rh * 64; // this wave's 64 rows
    const int colBase = cT * 128 + ch * 64; // this wave's 64 cols

    const ushort* pA = xb + (size_t)(rowBase + lane15) * DIM + quad * 8;
    const ushort* pB = xb + (size_t)(colBase + lane15) * DIM + quad * 8;

    v4f acc[4][4];
#pragma unroll
    for (int rf = 0; rf < 4; ++rf)
#pragma unroll
        for (int cf = 0; cf < 4; ++cf) {
            v4f z = {0.f, 0.f, 0.f, 0.f};
            acc[rf][cf] = z;
        }

    int4 a0[4], b0[4], a1[4], b1[4];
#pragma unroll
    for (int f = 0; f < 4; ++f) {           // prologue: k-step 0
        a0[f] = *(const int4*)(pA + f * 16 * DIM);
        b0[f] = *(const int4*)(pB + f * 16 * DIM);
    }

#pragma unroll 1
    for (int kk = 0; kk < 448; kk += 64) {  // 7 iters, 2 k-steps each
#pragma unroll
        for (int f = 0; f < 4; ++f) {       // prefetch k-step kk+32
            a1[f] = *(const int4*)(pA + f * 16 * DIM + kk + 32);
            b1[f] = *(const int4*)(pB + f * 16 * DIM + kk + 32);
        }
#pragma unroll
        for (int rf = 0; rf < 4; ++rf)
#pragma unroll
            for (int cf = 0; cf < 4; ++cf)
                acc[rf][cf] = __builtin_amdgcn_mfma_f32_16x16x32_bf16(
                    as_v8bf(a0[rf]), as_v8bf(b0[cf]), acc[rf][cf], 0, 0, 0);
#pragma unroll
        for (int f = 0; f < 4; ++f) {       // prefetch k-step kk+64
            a0[f] = *(const int4*)(pA + f * 16 * DIM + kk + 64);
            b0[f] = *(const int4*)(pB + f * 16 * DIM + kk + 64);
        }
#pragma unroll
        for (int rf = 0; rf < 4; ++rf)
#pragma unroll
            for (int cf = 0; cf < 4; ++cf)
                acc[rf][cf] = __builtin_amdgcn_mfma_f32_16x16x32_bf16(
                    as_v8bf(a1[rf]), as_v8bf(b1[cf]), acc[rf][cf], 0, 0, 0);
    }
    // tail: k-steps 448 (in a0/b0) and 480
#pragma unroll
    for (int f = 0; f < 4; ++f) {
        a1[f] = *(const int4*)(pA + f * 16 * DIM + 480);
        b1[f] = *(const int4*)(pB + f * 16 * DIM + 480);
    }
#pragma unroll
    for (int rf = 0; rf < 4; ++rf)
#pragma unroll
        for (int cf = 0; cf < 4; ++cf)
            acc[rf][cf] = __builtin_amdgcn_mfma_f32_16x16x32_bf16(
                as_v8bf(a0[rf]), as_v8bf(b0[cf]), acc[rf][cf], 0, 0, 0);
#pragma unroll
    for (int rf = 0; rf < 4; ++rf)
#pragma unroll
        for (int cf = 0; cf < 4; ++cf)
            acc[rf][cf] = __builtin_amdgcn_mfma_f32_16x16x32_bf16(
                as_v8bf(a1[rf]), as_v8bf(b1[cf]), acc[rf][cf], 0, 0, 0);

    // ---- epilogue: row-side argmax (C/D layout: col=lane15+16*cf, row=quad*4+e) ----
#pragma unroll
    for (int rf = 0; rf < 4; ++rf) {
#pragma unroll
        for (int e = 0; e < 4; ++e) {
            const int row = rowBase + rf * 16 + quad * 4 + e;
            float bv = -3.0e38f;
            int   bc = 0;
#pragma unroll
            for (int cf = 0; cf < 4; ++cf) {
                const float v = acc[rf][cf][e];
                const int col = colBase + lane15 + cf * 16;
                if (v > bv && col != row) { bv = v; bc = col; }
            }
            u64 packed = ((u64)fkey(bv) << 32) | (unsigned)(~bc);  // ~col: ties->lowest idx
#pragma unroll
            for (int m = 1; m < 16; m <<= 1) {
                u64 o = __shfl_xor(packed, m, 64);
                if (o > packed) packed = o;
            }
            if (lane15 == 0) atomicMax(&table[row], packed);
        }
    }

    // ---- epilogue: col-side (transposed) argmax for off-diagonal tiles ----
    if (rT != cT) {
#pragma unroll
        for (int cf = 0; cf < 4; ++cf) {
            const int col = colBase + lane15 + cf * 16;
            float bv = -3.0e38f;
            int   br_ = 0;
#pragma unroll
            for (int rf = 0; rf < 4; ++rf)
#pragma unroll
                for (int e = 0; e < 4; ++e) {
                    const float v = acc[rf][cf][e];
                    const int row = rowBase + rf * 16 + quad * 4 + e;
                    if (v > bv) { bv = v; br_ = row; }
                }
            u64 packed = ((u64)fkey(bv) << 32) | (unsigned)(~br_);
            u64 o = __shfl_xor(packed, 16, 64); if (o > packed) packed = o;
            o     = __shfl_xor(packed, 32, 64); if (o > packed) packed = o;
            if (quad == 0) atomicMax(&table[col], packed);
        }
    }
}

// ---------------- kernel 3: rho + loss epilogue (fp32 exact) ----------------
__global__ __launch_bounds__(256)
void rho_loss_kernel(const float* __restrict__ x, const u64* __restrict__ table,
                     float* __restrict__ out) {
    const int lane = threadIdx.x & 63;
    const int wave = threadIdx.x >> 6;
    const int waveGlobal = blockIdx.x * 4 + wave;   // 2048 waves

    float local = 0.f;
    for (int r8 = 0; r8 < 8; ++r8) {
        const int row = waveGlobal * 8 + r8;
        const u64 packed = table[row];
        const int nb = (int)(~(unsigned)(packed & 0xFFFFFFFFu));

        const float4* xr = (const float4*)(x + (size_t)row * DIM);
        const float4* xn = (const float4*)(x + (size_t)nb  * DIM);
        float s = 0.f;
#pragma unroll
        for (int tt = 0; tt < 2; ++tt) {
            float4 a = xr[lane * 2 + tt];
            float4 b = xn[lane * 2 + tt];
            float d0 = a.x - b.x + 1e-6f;
            float d1 = a.y - b.y + 1e-6f;
            float d2 = a.z - b.z + 1e-6f;
            float d3 = a.w - b.w + 1e-6f;
            s += d0 * d0 + d1 * d1 + d2 * d2 + d3 * d3;
        }
#pragma unroll
        for (int m = 1; m < 64; m <<= 1) s += __shfl_xor(s, m, 64);

        if (lane == 0) {
            float rho = sqrtf(s);
            local += logf(rho + 1e-8f);
        }
    }
    if (lane == 0) atomicAdd(out, -local * (1.0f / 16384.0f));
}

extern "C" void kernel_launch(void* const* d_in, const int* in_sizes, int n_in,
                              void* d_out, int out_size, void* d_ws, size_t ws_size,
                              hipStream_t stream) {
    const float* x = (const float*)d_in[0];

    // Workspace: [0, 16 MiB) bf16 x; then 16384 x u64 argmax table.
    ushort* xb    = (ushort*)d_ws;
    u64*    table = (u64*)((char*)d_ws + (size_t)N_ROWS * DIM * sizeof(ushort));
    float*  out   = (float*)d_out;

    hipMemsetAsync(out, 0, sizeof(float), stream);

    convert_bf16_kernel<<<2048, 256, 0, stream>>>(x, xb, table);
    argmax_dots_kernel<<<8256, 256, 0, stream>>>(xb, table);
    rho_loss_kernel<<<512, 256, 0, stream>>>(x, table, out);
}

// Round 8
// 263.070 us; speedup vs baseline: 2.2120x; 2.2120x over previous
//
#include <hip/hip_runtime.h>
#include <stdint.h>

#define N_ROWS 16384
#define DIM    512

typedef float v4f __attribute__((ext_vector_type(4)));
typedef unsigned long long u64;
typedef unsigned char u8;

// Monotonic float -> sortable u32 key
__device__ __forceinline__ unsigned fkey(float f) {
    unsigned u = __float_as_uint(f);
    return (u & 0x80000000u) ? ~u : (u | 0x80000000u);
}

// Async global->LDS, 16B per lane. LDS dest = wave-uniform base + lane*16.
__device__ __forceinline__ void gload_lds16(const void* g, void* l) {
    __builtin_amdgcn_global_load_lds(
        (const __attribute__((address_space(1))) unsigned int*)g,
        (__attribute__((address_space(3))) unsigned int*)l,
        16, 0, 0);
}

// ---------------- kernel 1: fp32 -> fp8 e4m3 convert (+ table zero-init) ----------------
// HW RNE; x ~ N(0,1), e4m3 max 448 -> no saturation. Validated in r5 (absmax 0.0).
__global__ __launch_bounds__(256)
void convert_fp8_kernel(const float* __restrict__ x, unsigned* __restrict__ x8,
                        u64* __restrict__ table) {
    int tid    = blockIdx.x * blockDim.x + threadIdx.x;
    int stride = gridDim.x * blockDim.x;
    if (tid < N_ROWS) table[tid] = 0;
    const float4* x4 = (const float4*)x;
    const int n4 = (N_ROWS * DIM) / 4;
    for (int i = tid; i < n4; i += stride) {
        float4 v = x4[i];
        int b = __builtin_amdgcn_cvt_pk_fp8_f32(v.x, v.y, 0, false);   // bytes 0,1
        b     = __builtin_amdgcn_cvt_pk_fp8_f32(v.z, v.w, b, true);    // bytes 2,3
        x8[i] = (unsigned)b;
    }
}

// ---------------- kernel 2: symmetric tiled fp8 GEMM + fused argmax ----------------
// Triangle-fold schedule (r3): b = u*64 + p; u<=p -> (127-p,127-u), else (p,u-1).
// r8 = r6 structure with fp8 e4m3 + non-scaled mfma_f32_16x16x32_fp8_fp8 (2-VGPR
// "long" operands -> VGPR budget stays ~r3, unlike r5's v8i disaster):
//   BK=128 fp8 in the SAME 32 KB LDS -> 4 K-rounds instead of 8 (halves the
//   per-round barrier/vmcnt-drain events = the measured dominant stall),
//   halves staging bytes and LDS read bytes. MFMA count/rate unchanged.
// LDS layout per matrix (16 KB, r6's swizzle at 16-fp8 chunks): tile = 128 rows
// x 128 k-bytes = 128 x 8 chunks. Slot (row, sk) holds chunk kc = sk ^ (row&7).
//  * staging lane L: row=L>>3, sk=L&7 -> src kc=(L&7)^(row&7); 8-lane groups
//    load full 128 B rows -> coalesced.
//  * frag read (k-step s, quad q, lane15 l): wants 8 B at kc=2s+(q>>1), half
//    q&1 of row rf*16+l -> addr = row*128 + ((2s+(q>>1))^(l&7))*16 + (q&1)*8.
//    ds_read_b64 natural 16-lane phases: banks (c^(l&7))*4+2(q&1) -> 2-way
//    aliasing = free (m136).
__global__ __launch_bounds__(256)
void argmax_dots_kernel(const u8* __restrict__ xb, u64* __restrict__ table) {
    __shared__ __attribute__((aligned(16))) u8 ldsA[128 * 128];  // 16 KB
    __shared__ __attribute__((aligned(16))) u8 ldsB[128 * 128];  // 16 KB

    const int u = blockIdx.x >> 6;
    const int p = blockIdx.x & 63;
    const int rT = (u <= p) ? (127 - p) : p;
    const int cT = (u <= p) ? (127 - u) : (u - 1);

    const int t      = threadIdx.x;
    const int lane   = t & 63;
    const int wave   = t >> 6;
    const int lane15 = lane & 15;
    const int quad   = lane >> 4;
    const int rh = wave >> 1;               // row half of the 128x128 tile
    const int ch = wave & 1;                // col half

    const int rowBase = rT * 128;
    const int colBase = cT * 128;

    // Staging sources: 4 issues per matrix per round, coalesced row-major.
    const u8* gA[4];
    const u8* gB[4];
#pragma unroll
    for (int j = 0; j < 4; ++j) {
        const int L   = j * 256 + t;
        const int row = L >> 3;
        const int kc  = (L & 7) ^ (row & 7);       // swizzled source chunk
        gA[j] = xb + (size_t)(rowBase + row) * DIM + kc * 16;
        gB[j] = xb + (size_t)(colBase + row) * DIM + kc * 16;
    }
    const int dstOff = wave * 1024;         // + j*4096 per issue (bytes)

    // Per-lane frag address pieces: addr = base + rf*2048 + xorK[s]
    const int aBase = (rh * 64 + lane15) * 128 + (quad & 1) * 8;
    const int bBase = (ch * 64 + lane15) * 128 + (quad & 1) * 8;
    int xorK[4];
#pragma unroll
    for (int s = 0; s < 4; ++s)
        xorK[s] = ((2 * s + (quad >> 1)) ^ (lane15 & 7)) << 4;

    v4f acc[4][4];
#pragma unroll
    for (int rf = 0; rf < 4; ++rf)
#pragma unroll
        for (int cf = 0; cf < 4; ++cf) {
            v4f z = {0.f, 0.f, 0.f, 0.f};
            acc[rf][cf] = z;
        }

#pragma unroll
    for (int k = 0; k < 4; ++k) {           // 4 K-rounds of BK=128
        const int kk = k * 128;             // byte offset within a row
#pragma unroll
        for (int j = 0; j < 4; ++j) {
            gload_lds16(gA[j] + kk, (char*)ldsA + j * 4096 + dstOff);
            gload_lds16(gB[j] + kk, (char*)ldsB + j * 4096 + dstOff);
        }
        __syncthreads();                    // drains vmcnt; loads visible

#pragma unroll
        for (int s = 0; s < 4; ++s) {       // 4 k-steps of 32 fp8
            const int xs = xorK[s];
            long a8[4], b8[4];
#pragma unroll
            for (int rf = 0; rf < 4; ++rf)
                a8[rf] = *(const long*)(ldsA + aBase + rf * 2048 + xs);
#pragma unroll
            for (int cf = 0; cf < 4; ++cf)
                b8[cf] = *(const long*)(ldsB + bBase + cf * 2048 + xs);
#pragma unroll
            for (int rf = 0; rf < 4; ++rf)
#pragma unroll
                for (int cf = 0; cf < 4; ++cf)
                    acc[rf][cf] = __builtin_amdgcn_mfma_f32_16x16x32_fp8_fp8(
                        a8[rf], b8[cf], acc[rf][cf], 0, 0, 0);
        }
        __syncthreads();                    // protect LDS from next round's writes
    }

    // ---- epilogue: row-side argmax (C/D layout: col=lane15+16*cf, row=quad*4+e) ----
    const int colLane = colBase + ch * 64 + lane15;
#pragma unroll
    for (int rf = 0; rf < 4; ++rf) {
#pragma unroll
        for (int e = 0; e < 4; ++e) {
            const int row = rowBase + rh * 64 + rf * 16 + quad * 4 + e;
            float bv = -3.0e38f;
            int   bc = 0;
#pragma unroll
            for (int cf = 0; cf < 4; ++cf) {
                const float v = acc[rf][cf][e];
                const int col = colLane + cf * 16;
                if (v > bv && col != row) { bv = v; bc = col; }
            }
            u64 packed = ((u64)fkey(bv) << 32) | (unsigned)(~bc);  // ~col: ties->lowest idx
#pragma unroll
            for (int m = 1; m < 16; m <<= 1) {
                u64 o = __shfl_xor(packed, m, 64);
                if (o > packed) packed = o;
            }
            if (lane15 == 0) atomicMax(&table[row], packed);
        }
    }

    // ---- epilogue: col-side (transposed) argmax for off-diagonal tiles ----
    if (rT != cT) {
#pragma unroll
        for (int cf = 0; cf < 4; ++cf) {
            const int col = colLane + cf * 16;
            float bv = -3.0e38f;
            int   br_ = 0;
#pragma unroll
            for (int rf = 0; rf < 4; ++rf)
#pragma unroll
                for (int e = 0; e < 4; ++e) {
                    const float v = acc[rf][cf][e];
                    const int row = rowBase + rh * 64 + rf * 16 + quad * 4 + e;
                    if (v > bv) { bv = v; br_ = row; }
                }
            u64 packed = ((u64)fkey(bv) << 32) | (unsigned)(~br_);
            u64 o = __shfl_xor(packed, 16, 64); if (o > packed) packed = o;
            o     = __shfl_xor(packed, 32, 64); if (o > packed) packed = o;
            if (quad == 0) atomicMax(&table[col], packed);
        }
    }
}

// ---------------- kernel 3: rho + loss epilogue (fp32 exact) ----------------
__global__ __launch_bounds__(256)
void rho_loss_kernel(const float* __restrict__ x, const u64* __restrict__ table,
                     float* __restrict__ out) {
    const int lane = threadIdx.x & 63;
    const int wave = threadIdx.x >> 6;
    const int waveGlobal = blockIdx.x * 4 + wave;   // 2048 waves

    float local = 0.f;
    for (int r8 = 0; r8 < 8; ++r8) {
        const int row = waveGlobal * 8 + r8;
        const u64 packed = table[row];
        const int nb = (int)(~(unsigned)(packed & 0xFFFFFFFFu));

        const float4* xr = (const float4*)(x + (size_t)row * DIM);
        const float4* xn = (const float4*)(x + (size_t)nb  * DIM);
        float s = 0.f;
#pragma unroll
        for (int tt = 0; tt < 2; ++tt) {
            float4 a = xr[lane * 2 + tt];
            float4 b = xn[lane * 2 + tt];
            float d0 = a.x - b.x + 1e-6f;
            float d1 = a.y - b.y + 1e-6f;
            float d2 = a.z - b.z + 1e-6f;
            float d3 = a.w - b.w + 1e-6f;
            s += d0 * d0 + d1 * d1 + d2 * d2 + d3 * d3;
        }
#pragma unroll
        for (int m = 1; m < 64; m <<= 1) s += __shfl_xor(s, m, 64);

        if (lane == 0) {
            float rho = sqrtf(s);
            local += logf(rho + 1e-8f);
        }
    }
    if (lane == 0) atomicAdd(out, -local * (1.0f / 16384.0f));
}

extern "C" void kernel_launch(void* const* d_in, const int* in_sizes, int n_in,
                              void* d_out, int out_size, void* d_ws, size_t ws_size,
                              hipStream_t stream) {
    const float* x = (const float*)d_in[0];

    // Workspace: [0, 8 MiB) fp8 x; then 16384 x u64 argmax table.
    u8*    xb    = (u8*)d_ws;
    u64*   table = (u64*)((char*)d_ws + (size_t)N_ROWS * DIM);
    float* out   = (float*)d_out;

    hipMemsetAsync(out, 0, sizeof(float), stream);

    convert_fp8_kernel<<<2048, 256, 0, stream>>>(x, (unsigned*)xb, table);
    argmax_dots_kernel<<<8256, 256, 0, stream>>>(xb, table);
    rho_loss_kernel<<<512, 256, 0, stream>>>(x, table, out);
}